// Round 4
// baseline (663.883 us; speedup 1.0000x reference)
//
#include <hip/hip_runtime.h>
#include <math.h>

// AttentionPooling: B=32 S=4096 E=1024 H=16 D=64
// scores[b,h,s] = (Wk_h^T q[b,h]).x[b,s]/8 ; ctx[b,h] = Wv_h (sum_s attn x[b,s]) + bv
// SINGLE streaming pass over x: fused flash-style score + online-softmax weighted sum.

constexpr int cB = 32, cS = 4096, cE = 1024, cH = 16, cD = 64;
constexpr int cCK = 8;          // chunks per b (512 s each)
constexpr int cSUB = 32;        // sub-chunks per chunk (16 s each)

// ws layout in floats
constexpr size_t OFF_P    = 0;                     // B*H*E   = 524288
constexpr size_t OFF_C    = OFF_P + 524288;        // B*H     = 512
constexpr size_t OFF_Q    = OFF_C + 512;           // B*E     = 32768
constexpr size_t OFF_SC   = OFF_Q + 32768;         // B*H*S   = 2097152 masked scores
constexpr size_t OFF_SM   = OFF_SC + 2097152;      // B*H*CK  = 4096 chunk max
constexpr size_t OFF_SL   = OFF_SM + 4096;         // B*H*CK  = 4096 chunk expsum
constexpr size_t OFF_MF   = OFF_SL + 4096;         // B*H     = 512 row max
constexpr size_t OFF_IL   = OFF_MF + 512;          // B*H     = 512 inv rowsum
constexpr size_t OFF_CTX  = OFF_IL + 512;          // B*E     = 32768
constexpr size_t OFF_PART = OFF_CTX + 32768;       // B*CK*H*E = 4194304
// total ~ 6.9M floats = 27.6 MB

__device__ inline float wave_sum64(float v) {
#pragma unroll
  for (int m = 1; m < 64; m <<= 1) v += __shfl_xor(v, m);
  return v;
}

// ---------------- Kernel 1a: q[b,:] = Wq @ x[b,0,:] + bq ----------------
__global__ __launch_bounds__(256) void k1a_q(const float* __restrict__ x,
                                             const float* __restrict__ w,
                                             const float* __restrict__ bias,
                                             float* __restrict__ q) {
  int b = blockIdx.x >> 3, blk = blockIdx.x & 7;
  int tid = threadIdx.x;
  __shared__ float x0[cE];
  ((float4*)x0)[tid] = ((const float4*)(x + (size_t)b * cS * cE))[tid];
  __syncthreads();
  int row = blk * 128 + (tid >> 1);
  int half = tid & 1;
  const float* wr = w + (size_t)row * cE + half * 512;
  const float* xl = x0 + half * 512;
  float acc = 0.f;
#pragma unroll 4
  for (int j = 0; j < 128; ++j) {
    float4 a = *(const float4*)(wr + j * 4);
    float4 xv = *(const float4*)(xl + j * 4);
    acc = fmaf(a.x, xv.x, acc); acc = fmaf(a.y, xv.y, acc);
    acc = fmaf(a.z, xv.z, acc); acc = fmaf(a.w, xv.w, acc);
  }
  float tot = acc + __shfl_xor(acc, 1);
  if (!half) q[b * cE + row] = tot + bias[row];
}

// ---------------- Kernel 1b: p[b,h,e] = 0.125 * sum_d Wk[h*64+d, e] q[b, h*64+d] ------
__global__ __launch_bounds__(256) void k1b_p(const float* __restrict__ w,
                                             const float* __restrict__ bvec,
                                             const float* __restrict__ q,
                                             float* __restrict__ p,
                                             float* __restrict__ cb) {
  int b = blockIdx.x >> 3, sub = blockIdx.x & 7;
  int ec = sub >> 1, hh = sub & 1;
  int tid = threadIdx.x;
  int e = ec * 256 + tid;
  __shared__ float ql[cE];
  ((float4*)ql)[tid] = ((const float4*)(q + (size_t)b * cE))[tid];
  __syncthreads();
  for (int hi = 0; hi < 8; ++hi) {
    int h = hh * 8 + hi;
    float acc = 0.f;
    const float* wb = w + (size_t)(cE + h * cD) * cE + e;
    const float* qh = ql + h * cD;
#pragma unroll 8
    for (int d = 0; d < cD; ++d) acc = fmaf(wb[(size_t)d * cE], qh[d], acc);
    p[(size_t)(b * cH + h) * cE + e] = 0.125f * acc;
  }
  if (ec == 0 && tid < 8) {
    int h = hh * 8 + tid;
    float cacc = 0.f;
    for (int d = 0; d < cD; ++d) cacc = fmaf(ql[h * cD + d], bvec[cE + h * cD + d], cacc);
    cb[b * cH + h] = 0.125f * cacc;
  }
}

// ---------------- kfuse: fused scores + mask + online-softmax weighted sum ----------
// grid 256 = B*8 chunks of 512 s. 1 block/CU (128.3 KB LDS). Per 16-s sub-chunk:
//   [ds_write staged regs -> xt] [issue next loads] [barrier]
//   phase A (thread = (s,h)): score = p_h . x_s + c_h, mask, store, group-softmax update
//   [barrier] phase B (thread = e4): acc[h] = acc[h]*rescale + sum_s ex[s][h]*x[s][e]
//   [barrier]
// x tile in LDS is float4-swizzled: idx4 = s*256 + (e4 ^ s)  (conflict-free both phases).
__global__ __launch_bounds__(256, 1) void kfuse(const float* __restrict__ x,
                                                const float* __restrict__ p,
                                                const float* __restrict__ cb,
                                                const int* __restrict__ mask,
                                                float* __restrict__ scores,
                                                float* __restrict__ statsM,
                                                float* __restrict__ statsL,
                                                float* __restrict__ part) {
  __shared__ __align__(16) float pl[cH * cE];    // 64 KB  p[h][e]
  __shared__ __align__(16) float xt[16 * cE];    // 64 KB  swizzled x tile
  __shared__ __align__(16) float exb[16 * cH];   // ex[s][h]
  __shared__ __align__(16) float scl[cH];        // per-h rescale
  int b = blockIdx.x >> 3, ck = blockIdx.x & 7;
  int tid = threadIdx.x;
  int sA = tid & 15, hA = tid >> 4;
  int s0g = ck * 512;

  // stage p[b] -> LDS (coalesced)
#pragma unroll
  for (int j = 0; j < 16; ++j) {
    int idx4 = j * 256 + tid;
    ((float4*)pl)[idx4] =
        *(const float4*)(p + (size_t)(b * cH + (idx4 >> 8)) * cE + (size_t)(idx4 & 255) * 4);
  }
  float cbh = cb[b * cH + hA];

  float4 acc[16];
#pragma unroll
  for (int h = 0; h < cH; ++h) acc[h] = make_float4(0.f, 0.f, 0.f, 0.f);
  float m_run = -1e30f, l_run = 0.f;

  // staging: thread covers row s = tid>>4, e4 = (tid&15) + 16j
  const float* xbase = x + ((size_t)b * cS + s0g + (tid >> 4)) * cE + (size_t)(tid & 15) * 4;
  int sw = tid >> 4;          // staging row
  int e4b = tid & 15;         // staging e4 base
  float4 rv[16];
#pragma unroll
  for (int j = 0; j < 16; ++j) rv[j] = *(const float4*)(xbase + j * 64);
  __syncthreads();            // pl ready

  float4* xt4 = (float4*)xt;
  const float4* ph4 = (const float4*)(pl + hA * cE);
  const float4* exb4 = (const float4*)exb;
  const float4* scl4 = (const float4*)scl;

  for (int sub = 0; sub < cSUB; ++sub) {
    // ds_write staged sub-chunk (implicit vmcnt wait on rv)
#pragma unroll
    for (int j = 0; j < 16; ++j) {
      int e4 = e4b + 16 * j;
      xt4[sw * 256 + (e4 ^ sw)] = rv[j];
    }
    // T14: issue next sub-chunk's loads now; consumed next iteration
    if (sub < cSUB - 1) {
      const float* xn = xbase + (size_t)(sub + 1) * 16 * cE;
#pragma unroll
      for (int j = 0; j < 16; ++j) rv[j] = *(const float4*)(xn + j * 64);
    }
    __syncthreads();          // xt ready

    // ---- phase A: thread (sA, hA) computes score for s = sub*16+sA, head hA
    float d0 = 0.f, d1 = 0.f, d2 = 0.f, d3 = 0.f;
#pragma unroll 8
    for (int e4 = 0; e4 < 256; e4 += 4) {
      float4 x0 = xt4[sA * 256 + ((e4 + 0) ^ sA)];
      float4 p0 = ph4[e4 + 0];
      d0 = fmaf(x0.x, p0.x, d0); d0 = fmaf(x0.y, p0.y, d0);
      d0 = fmaf(x0.z, p0.z, d0); d0 = fmaf(x0.w, p0.w, d0);
      float4 x1 = xt4[sA * 256 + ((e4 + 1) ^ sA)];
      float4 p1 = ph4[e4 + 1];
      d1 = fmaf(x1.x, p1.x, d1); d1 = fmaf(x1.y, p1.y, d1);
      d1 = fmaf(x1.z, p1.z, d1); d1 = fmaf(x1.w, p1.w, d1);
      float4 x2 = xt4[sA * 256 + ((e4 + 2) ^ sA)];
      float4 p2 = ph4[e4 + 2];
      d2 = fmaf(x2.x, p2.x, d2); d2 = fmaf(x2.y, p2.y, d2);
      d2 = fmaf(x2.z, p2.z, d2); d2 = fmaf(x2.w, p2.w, d2);
      float4 x3 = xt4[sA * 256 + ((e4 + 3) ^ sA)];
      float4 p3 = ph4[e4 + 3];
      d3 = fmaf(x3.x, p3.x, d3); d3 = fmaf(x3.y, p3.y, d3);
      d3 = fmaf(x3.z, p3.z, d3); d3 = fmaf(x3.w, p3.w, d3);
    }
    float score = (d0 + d1) + (d2 + d3) + cbh;
    int sg = s0g + sub * 16 + sA;
    if (mask[(size_t)b * cS + sg]) score = -1e30f;
    scores[(size_t)(b * cH + hA) * cS + sg] = score;
    // group (16-lane) softmax update
    float gm = score;
#pragma unroll
    for (int m = 1; m < 16; m <<= 1) gm = fmaxf(gm, __shfl_xor(gm, m));
    float mnew = fmaxf(m_run, gm);
    float rs = __expf(m_run - mnew);
    float ex = __expf(score - mnew);
    float gs = ex;
#pragma unroll
    for (int m = 1; m < 16; m <<= 1) gs += __shfl_xor(gs, m);
    l_run = l_run * rs + gs;
    m_run = mnew;
    exb[sA * cH + hA] = ex;
    if (sA == 0) scl[hA] = rs;
    __syncthreads();          // exb/scl ready

    // ---- phase B: thread owns e4 = tid (4 e-columns)
#pragma unroll
    for (int k = 0; k < 4; ++k) {
      float4 sv = scl4[k];
      acc[k * 4 + 0].x *= sv.x; acc[k * 4 + 0].y *= sv.x; acc[k * 4 + 0].z *= sv.x; acc[k * 4 + 0].w *= sv.x;
      acc[k * 4 + 1].x *= sv.y; acc[k * 4 + 1].y *= sv.y; acc[k * 4 + 1].z *= sv.y; acc[k * 4 + 1].w *= sv.y;
      acc[k * 4 + 2].x *= sv.z; acc[k * 4 + 2].y *= sv.z; acc[k * 4 + 2].z *= sv.z; acc[k * 4 + 2].w *= sv.z;
      acc[k * 4 + 3].x *= sv.w; acc[k * 4 + 3].y *= sv.w; acc[k * 4 + 3].z *= sv.w; acc[k * 4 + 3].w *= sv.w;
    }
#pragma unroll 4
    for (int s = 0; s < 16; ++s) {
      float4 xv = xt4[s * 256 + (tid ^ s)];
      float4 ea = exb4[s * 4 + 0];
      float4 eb = exb4[s * 4 + 1];
      float4 ec = exb4[s * 4 + 2];
      float4 ed = exb4[s * 4 + 3];
      float aa[16] = {ea.x, ea.y, ea.z, ea.w, eb.x, eb.y, eb.z, eb.w,
                      ec.x, ec.y, ec.z, ec.w, ed.x, ed.y, ed.z, ed.w};
#pragma unroll
      for (int h = 0; h < cH; ++h) {
        acc[h].x = fmaf(aa[h], xv.x, acc[h].x);
        acc[h].y = fmaf(aa[h], xv.y, acc[h].y);
        acc[h].z = fmaf(aa[h], xv.z, acc[h].z);
        acc[h].w = fmaf(aa[h], xv.w, acc[h].w);
      }
    }
    __syncthreads();          // before next sub-chunk overwrites xt
  }

  // epilogue: part + stats
  float* pb = part + (size_t)(b * cCK + ck) * cH * cE + (size_t)tid * 4;
#pragma unroll
  for (int h = 0; h < cH; ++h) *(float4*)(pb + (size_t)h * cE) = acc[h];
  if (sA == 0) {
    statsM[(b * cH + hA) * cCK + ck] = m_run;
    statsL[(b * cH + hA) * cCK + ck] = l_run;
  }
}

// ---------------- k5: combine chunks -> y; ctx = Wv_h y + bv; emit Mf/iLf ----------
__global__ __launch_bounds__(256) void k5_ctx(const float* __restrict__ w,
                                              const float* __restrict__ bvec,
                                              const float* __restrict__ part,
                                              const float* __restrict__ statsM,
                                              const float* __restrict__ statsL,
                                              float* __restrict__ ctx,
                                              float* __restrict__ Mf,
                                              float* __restrict__ iLf) {
  int b = blockIdx.x >> 4, h = blockIdx.x & 15;
  int bh = b * cH + h;
  int tid = threadIdx.x;
  __shared__ float yl[cE];
  float M = -3e38f;
#pragma unroll
  for (int c = 0; c < cCK; ++c) M = fmaxf(M, statsM[bh * cCK + c]);
  float L = 0.f;
  float wgt[cCK];
#pragma unroll
  for (int c = 0; c < cCK; ++c) {
    wgt[c] = __expf(statsM[bh * cCK + c] - M);
    L += statsL[bh * cCK + c] * wgt[c];
  }
  float iL = 1.0f / L;
  if (blockIdx.x < 512 && tid == 0) { Mf[bh] = M; iLf[bh] = iL; }
  float4 a = make_float4(0.f, 0.f, 0.f, 0.f);
  const float* pb = part + (size_t)b * cCK * cH * cE + (size_t)h * cE + (size_t)tid * 4;
#pragma unroll
  for (int c = 0; c < cCK; ++c) {
    float4 v = *(const float4*)(pb + (size_t)c * cH * cE);
    a.x = fmaf(v.x, wgt[c], a.x); a.y = fmaf(v.y, wgt[c], a.y);
    a.z = fmaf(v.z, wgt[c], a.z); a.w = fmaf(v.w, wgt[c], a.w);
  }
  a.x *= iL; a.y *= iL; a.z *= iL; a.w *= iL;
  *(float4*)(yl + tid * 4) = a;
  __syncthreads();
  int wid = tid >> 6, lane = tid & 63;
  for (int i = 0; i < 16; ++i) {
    int d = wid * 16 + i;
    const float* wr = w + (size_t)(2 * cE + h * cD + d) * cE + lane * 16;
    const float* yr = yl + lane * 16;
    float partial = 0.f;
#pragma unroll
    for (int j = 0; j < 4; ++j) {
      float4 wv = *(const float4*)(wr + j * 4);
      float4 yv = *(const float4*)(yr + j * 4);
      partial = fmaf(wv.x, yv.x, partial); partial = fmaf(wv.y, yv.y, partial);
      partial = fmaf(wv.z, yv.z, partial); partial = fmaf(wv.w, yv.w, partial);
    }
    partial = wave_sum64(partial);
    if (lane == 0) ctx[b * cE + h * cD + d] = partial + bvec[2 * cE + h * cD + d];
  }
}

// ---------------- kmean: attn_weights[b,0,s] = mean_h exp(score - M_h)*iL_h ----------
__global__ __launch_bounds__(256) void kmean(const float* __restrict__ scores,
                                             const float* __restrict__ Mf,
                                             const float* __restrict__ iLf,
                                             float* __restrict__ out) {
  int idx = blockIdx.x * 256 + threadIdx.x;
  int b = idx >> 12, s = idx & 4095;
  float sum = 0.f;
#pragma unroll
  for (int h = 0; h < cH; ++h) {
    float v = scores[(size_t)(b * cH + h) * cS + s];
    sum += __expf(v - Mf[b * cH + h]) * iLf[b * cH + h];
  }
  out[cB * cE + (size_t)b * cS + s] = sum * (1.0f / 16.0f);
}

// ---------------- k6: out[b,:] = out_w @ ctx[b,:] + out_b ----------------
__global__ __launch_bounds__(256) void k6_out(const float* __restrict__ w,
                                              const float* __restrict__ bvec,
                                              const float* __restrict__ ctx,
                                              float* __restrict__ out) {
  int b = blockIdx.x >> 3, br = blockIdx.x & 7;
  int tid = threadIdx.x;
  __shared__ float cl[cE];
  ((float4*)cl)[tid] = ((const float4*)(ctx + (size_t)b * cE))[tid];
  __syncthreads();
  int wid = tid >> 6, lane = tid & 63;
  for (int i = 0; i < 32; ++i) {
    int row = br * 128 + wid * 32 + i;
    const float* wr = w + (size_t)row * cE + lane * 16;
    const float* cr = cl + lane * 16;
    float partial = 0.f;
#pragma unroll
    for (int j = 0; j < 4; ++j) {
      float4 wv = *(const float4*)(wr + j * 4);
      float4 cv = *(const float4*)(cr + j * 4);
      partial = fmaf(wv.x, cv.x, partial); partial = fmaf(wv.y, cv.y, partial);
      partial = fmaf(wv.z, cv.z, partial); partial = fmaf(wv.w, cv.w, partial);
    }
    partial = wave_sum64(partial);
    if (lane == 0) out[(size_t)b * cE + row] = partial + bvec[row];
  }
}

extern "C" void kernel_launch(void* const* d_in, const int* in_sizes, int n_in,
                              void* d_out, int out_size, void* d_ws, size_t ws_size,
                              hipStream_t stream) {
  const float* x = (const float*)d_in[0];
  const int* mask = (const int*)d_in[1];
  const float* in_proj_w = (const float*)d_in[2];
  const float* in_proj_b = (const float*)d_in[3];
  const float* out_w = (const float*)d_in[4];
  const float* out_b = (const float*)d_in[5];
  float* out = (float*)d_out;
  float* W = (float*)d_ws;

  float* p = W + OFF_P;
  float* cb = W + OFF_C;
  float* q = W + OFF_Q;
  float* scores = W + OFF_SC;
  float* statsM = W + OFF_SM;
  float* statsL = W + OFF_SL;
  float* Mf = W + OFF_MF;
  float* iLf = W + OFF_IL;
  float* ctx = W + OFF_CTX;
  float* part = W + OFF_PART;

  k1a_q<<<256, 256, 0, stream>>>(x, in_proj_w, in_proj_b, q);
  k1b_p<<<256, 256, 0, stream>>>(in_proj_w, in_proj_b, q, p, cb);
  kfuse<<<256, 256, 0, stream>>>(x, p, cb, mask, scores, statsM, statsL, part);
  k5_ctx<<<512, 256, 0, stream>>>(in_proj_w, in_proj_b, part, statsM, statsL, ctx, Mf, iLf);
  kmean<<<512, 256, 0, stream>>>(scores, Mf, iLf, out);
  k6_out<<<256, 256, 0, stream>>>(out_w, out_b, ctx, out);
}

// Round 5
// 412.821 us; speedup vs baseline: 1.6082x; 1.6082x over previous
//
#include <hip/hip_runtime.h>
#include <math.h>

// AttentionPooling: B=32 S=4096 E=1024 H=16 D=64
// scores[b,h,s] = (Wk_h^T q[b,h]).x[b,s]/8 ; ctx[b,h] = Wv_h (sum_s attn x[b,s]) + bv
// Two streaming x-passes (k2 scores+chunk-stats, k4 exp-normalize+weighted-sum+mean).

constexpr int cB = 32, cS = 4096, cE = 1024, cH = 16, cD = 64, cNC = 16;

// ws layout in floats
constexpr size_t OFF_P    = 0;                     // B*H*E   = 524288
constexpr size_t OFF_C    = OFF_P + 524288;        // B*H     = 512
constexpr size_t OFF_Q    = OFF_C + 512;           // B*E     = 32768
constexpr size_t OFF_SC   = OFF_Q + 32768;         // B*H*S   = 2097152 masked scores
constexpr size_t OFF_SM   = OFF_SC + 2097152;      // B*H*NC  = 8192 chunk max
constexpr size_t OFF_SL   = OFF_SM + 8192;         // B*H*NC  = 8192 chunk expsum
constexpr size_t OFF_MF   = OFF_SL + 8192;         // B*H     = 512 row max
constexpr size_t OFF_IL   = OFF_MF + 512;          // B*H     = 512 inv rowsum
constexpr size_t OFF_CTX  = OFF_IL + 512;          // B*E     = 32768
constexpr size_t OFF_PART = OFF_CTX + 32768;       // B*NC*H*E = 8388608

__device__ inline float wave_max64(float v) {
#pragma unroll
  for (int m = 1; m < 64; m <<= 1) v = fmaxf(v, __shfl_xor(v, m));
  return v;
}
__device__ inline float wave_sum64(float v) {
#pragma unroll
  for (int m = 1; m < 64; m <<= 1) v += __shfl_xor(v, m);
  return v;
}

// ---------------- Kernel 1a: q[b,:] = Wq @ x[b,0,:] + bq ----------------
__global__ __launch_bounds__(256) void k1a_q(const float* __restrict__ x,
                                             const float* __restrict__ w,
                                             const float* __restrict__ bias,
                                             float* __restrict__ q) {
  int b = blockIdx.x >> 3, blk = blockIdx.x & 7;
  int tid = threadIdx.x;
  __shared__ float x0[cE];
  ((float4*)x0)[tid] = ((const float4*)(x + (size_t)b * cS * cE))[tid];
  __syncthreads();
  int row = blk * 128 + (tid >> 1);
  int half = tid & 1;
  const float* wr = w + (size_t)row * cE + half * 512;
  const float* xl = x0 + half * 512;
  float acc = 0.f;
#pragma unroll 4
  for (int j = 0; j < 128; ++j) {
    float4 a = *(const float4*)(wr + j * 4);
    float4 xv = *(const float4*)(xl + j * 4);
    acc = fmaf(a.x, xv.x, acc); acc = fmaf(a.y, xv.y, acc);
    acc = fmaf(a.z, xv.z, acc); acc = fmaf(a.w, xv.w, acc);
  }
  float tot = acc + __shfl_xor(acc, 1);
  if (!half) q[b * cE + row] = tot + bias[row];
}

// ---------------- Kernel 1b: p[b,h,e] = 0.125 * sum_d Wk[h*64+d, e] q[b, h*64+d] ------
__global__ __launch_bounds__(256) void k1b_p(const float* __restrict__ w,
                                             const float* __restrict__ bvec,
                                             const float* __restrict__ q,
                                             float* __restrict__ p,
                                             float* __restrict__ cb) {
  int b = blockIdx.x >> 3, sub = blockIdx.x & 7;
  int ec = sub >> 1, hh = sub & 1;
  int tid = threadIdx.x;
  int e = ec * 256 + tid;
  __shared__ float ql[cE];
  ((float4*)ql)[tid] = ((const float4*)(q + (size_t)b * cE))[tid];
  __syncthreads();
  for (int hi = 0; hi < 8; ++hi) {
    int h = hh * 8 + hi;
    float acc = 0.f;
    const float* wb = w + (size_t)(cE + h * cD) * cE + e;
    const float* qh = ql + h * cD;
#pragma unroll 8
    for (int d = 0; d < cD; ++d) acc = fmaf(wb[(size_t)d * cE], qh[d], acc);
    p[(size_t)(b * cH + h) * cE + e] = 0.125f * acc;
  }
  if (ec == 0 && tid < 8) {
    int h = hh * 8 + tid;
    float cacc = 0.f;
    for (int d = 0; d < cD; ++d) cacc = fmaf(ql[h * cD + d], bvec[cE + h * cD + d], cacc);
    cb[b * cH + h] = 0.125f * cacc;
  }
}

// ---------------- Kernel 2: scores + mask + per-chunk softmax stats ----------------
// grid 512 = B*16 s-chunks of 256, block 256 (64 s-threads x 4 h-waves, tile 4s x 4h).
// x double-buffered in LDS (swizzled); p read via wave-uniform scalar loads.
__global__ __launch_bounds__(256) void k2_scores(const float* __restrict__ x,
                                                 const float* __restrict__ p,
                                                 const float* __restrict__ cbias,
                                                 const int* __restrict__ mask,
                                                 float* __restrict__ scores,
                                                 float* __restrict__ statsM,
                                                 float* __restrict__ statsL) {
  __shared__ float xT[2][32 * 256];   // [buf][e][swizzled s], 2x32 KB
  int bx = blockIdx.x;
  int b = bx >> 4, sc = bx & 15;
  int s_base = sc * 256;
  int tid = threadIdx.x;
  int s_t = tid & 63, h_t = tid >> 6;
  int h0 = __builtin_amdgcn_readfirstlane(h_t * 4);
  float acc[4][4];
#pragma unroll
  for (int i = 0; i < 4; ++i)
#pragma unroll
    for (int j = 0; j < 4; ++j) acc[i][j] = 0.f;

  const float* xb = x + ((size_t)b * cS + s_base) * cE;
  const float* __restrict__ pu = p + (size_t)(b * cH + h0) * cE;

  float4 sv[8];
  int r_ = tid >> 3, c4_ = tid & 7;

#pragma unroll
  for (int i = 0; i < 8; ++i)
    sv[i] = *(const float4*)(xb + (size_t)(i * 32 + r_) * cE + c4_ * 4);
  {
    float* xd = xT[0];
#pragma unroll
    for (int i = 0; i < 8; ++i) {
      int r = i * 32 + r_;
      float vv[4] = {sv[i].x, sv[i].y, sv[i].z, sv[i].w};
#pragma unroll
      for (int j = 0; j < 4; ++j) {
        int e = c4_ * 4 + j;
        int f = (e ^ (e >> 4)) & 15;
        xd[e * 256 + ((((r >> 2) ^ f) << 2) | (r & 3))] = vv[j];
      }
    }
  }
  __syncthreads();

  for (int kt = 1; kt <= 32; ++kt) {
    if (kt < 32) {
#pragma unroll
      for (int i = 0; i < 8; ++i)
        sv[i] = *(const float4*)(xb + (size_t)(i * 32 + r_) * cE + kt * 32 + c4_ * 4);
    }
    {
      const float* xs = xT[(kt - 1) & 1];
      const int kb = (kt - 1) * 32;
#pragma unroll 8
      for (int e = 0; e < 32; ++e) {
        int f = (e ^ (e >> 4)) & 15;
        float4 xv = *(const float4*)&xs[e * 256 + ((s_t ^ f) << 2)];
        float p0 = pu[kb + e];
        float p1 = pu[cE + kb + e];
        float p2 = pu[2 * cE + kb + e];
        float p3 = pu[3 * cE + kb + e];
        float xa[4] = {xv.x, xv.y, xv.z, xv.w};
        float pa[4] = {p0, p1, p2, p3};
#pragma unroll
        for (int si = 0; si < 4; ++si)
#pragma unroll
          for (int hj = 0; hj < 4; ++hj) acc[si][hj] = fmaf(xa[si], pa[hj], acc[si][hj]);
      }
    }
    if (kt < 32) {
      float* xd = xT[kt & 1];
#pragma unroll
      for (int i = 0; i < 8; ++i) {
        int r = i * 32 + r_;
        float vv[4] = {sv[i].x, sv[i].y, sv[i].z, sv[i].w};
#pragma unroll
        for (int j = 0; j < 4; ++j) {
          int e = c4_ * 4 + j;
          int f = (e ^ (e >> 4)) & 15;
          xd[e * 256 + ((((r >> 2) ^ f) << 2) | (r & 3))] = vv[j];
        }
      }
    }
    __syncthreads();
  }

  float4 cv = *(const float4*)(cbias + b * cH + h0);
  float ca[4] = {cv.x, cv.y, cv.z, cv.w};
  int4 m4 = *(const int4*)(mask + (size_t)b * cS + s_base + s_t * 4);
#pragma unroll
  for (int hj = 0; hj < 4; ++hj) {
    float v0 = m4.x ? -1e30f : acc[0][hj] + ca[hj];
    float v1 = m4.y ? -1e30f : acc[1][hj] + ca[hj];
    float v2 = m4.z ? -1e30f : acc[2][hj] + ca[hj];
    float v3 = m4.w ? -1e30f : acc[3][hj] + ca[hj];
    *(float4*)(scores + (size_t)(b * cH + h0 + hj) * cS + s_base + s_t * 4) =
        make_float4(v0, v1, v2, v3);
    float mx = fmaxf(fmaxf(v0, v1), fmaxf(v2, v3));
    float wm = wave_max64(mx);
    float es = __expf(v0 - wm) + __expf(v1 - wm) + __expf(v2 - wm) + __expf(v3 - wm);
    float wsum = wave_sum64(es);
    if (s_t == 0) {
      statsM[(size_t)(b * cH + h0 + hj) * cNC + sc] = wm;
      statsL[(size_t)(b * cH + h0 + hj) * cNC + sc] = wsum;
    }
  }
}

// ---------------- Kernel 3t: reduce chunk stats -> M[b,h], invL[b,h] ----------------
__global__ __launch_bounds__(64) void k3t_stats(const float* __restrict__ statsM,
                                                const float* __restrict__ statsL,
                                                float* __restrict__ Mf,
                                                float* __restrict__ iLf) {
  int bh = blockIdx.x * 64 + threadIdx.x;
  const float* sm = statsM + (size_t)bh * cNC;
  const float* sl = statsL + (size_t)bh * cNC;
  float M = -3e38f;
#pragma unroll
  for (int c = 0; c < cNC; ++c) M = fmaxf(M, sm[c]);
  float L = 0.f;
#pragma unroll
  for (int c = 0; c < cNC; ++c) L += sl[c] * __expf(sm[c] - M);
  Mf[bh] = M;
  iLf[bh] = 1.0f / L;
}

// ---------------- Kernel 4: exp-normalize + weighted sum + fused attn-mean ----------
// grid 512 = B*16 s-chunks of 256, block 256; thread owns 4 e x 16 h.
// attn staged per 64-s group in al[s][h] (pad 20): 4 b128 broadcast reads per s.
__global__ __launch_bounds__(256) void k4_wsum(const float* __restrict__ x,
                                               const float* __restrict__ scores,
                                               const float* __restrict__ Mf,
                                               const float* __restrict__ iLf,
                                               float* __restrict__ part,
                                               float* __restrict__ out) {
  __shared__ float al[2][64][20];
  int bx = blockIdx.x;
  int b = bx >> 4, sc = bx & 15;
  int tid = threadIdx.x;
  int wv = tid >> 6, lane = tid & 63;
  int e0 = tid * 4;
  const float* sb = scores + (size_t)b * cH * cS + sc * 256;
  int h0w = wv * 4;
  float M4[4], iL4[4];
#pragma unroll
  for (int j = 0; j < 4; ++j) {
    M4[j] = Mf[b * cH + h0w + j];
    iL4[j] = iLf[b * cH + h0w + j];
  }
  float4 acc[16];
#pragma unroll
  for (int h = 0; h < cH; ++h) acc[h] = make_float4(0.f, 0.f, 0.f, 0.f);

  // stage group 0
#pragma unroll
  for (int j = 0; j < 4; ++j) {
    float v = sb[(size_t)(h0w + j) * cS + lane];
    al[0][lane][h0w + j] = __expf(v - M4[j]) * iL4[j];
  }
  __syncthreads();

  const float* xg = x + ((size_t)b * cS + sc * 256) * cE + e0;
  for (int g = 0; g < 4; ++g) {
    int buf = g & 1;
    if (g < 3) {
#pragma unroll
      for (int j = 0; j < 4; ++j) {
        float v = sb[(size_t)(h0w + j) * cS + (g + 1) * 64 + lane];
        al[buf ^ 1][lane][h0w + j] = __expf(v - M4[j]) * iL4[j];
      }
    }
    const float* xs = xg + (size_t)g * 64 * cE;
#pragma unroll 4
    for (int s = 0; s < 64; ++s) {
      float4 xv = *(const float4*)(xs + (size_t)s * cE);
      const float4* ar = (const float4*)al[buf][s];
      float4 a0 = ar[0], a1 = ar[1], a2 = ar[2], a3 = ar[3];
      float aa[16] = {a0.x, a0.y, a0.z, a0.w, a1.x, a1.y, a1.z, a1.w,
                      a2.x, a2.y, a2.z, a2.w, a3.x, a3.y, a3.z, a3.w};
#pragma unroll
      for (int h = 0; h < cH; ++h) {
        acc[h].x = fmaf(aa[h], xv.x, acc[h].x);
        acc[h].y = fmaf(aa[h], xv.y, acc[h].y);
        acc[h].z = fmaf(aa[h], xv.z, acc[h].z);
        acc[h].w = fmaf(aa[h], xv.w, acc[h].w);
      }
    }
    // fused attn-weights mean: wave g handles its group's 64 s (s = lane)
    if (wv == g) {
      const float4* ar = (const float4*)al[buf][lane];
      float4 a0 = ar[0], a1 = ar[1], a2 = ar[2], a3 = ar[3];
      float ms = (a0.x + a0.y + a0.z + a0.w) + (a1.x + a1.y + a1.z + a1.w) +
                 (a2.x + a2.y + a2.z + a2.w) + (a3.x + a3.y + a3.z + a3.w);
      out[cB * cE + (size_t)b * cS + sc * 256 + g * 64 + lane] = ms * (1.0f / 16.0f);
    }
    __syncthreads();
  }

  float* pb = part + ((size_t)(b * cNC + sc) * cH) * cE + e0;
#pragma unroll
  for (int h = 0; h < cH; ++h) *(float4*)(pb + (size_t)h * cE) = acc[h];
}

// ---------------- Kernel 5: y[b,h,:] = sum_ck part; ctx = Wv_h y + bv ----------------
// grid 128 = 16 h x 8 b-quads. Wv_h staged-read once per block; part read once total.
__global__ __launch_bounds__(256) void k5_ctx(const float* __restrict__ w,
                                              const float* __restrict__ bvec,
                                              const float* __restrict__ part,
                                              float* __restrict__ ctx) {
  int h = blockIdx.x >> 3, bq = blockIdx.x & 7;
  int b0 = bq * 4;
  int tid = threadIdx.x;
  __shared__ float yl[4][1028];
  int bb = tid >> 6, c4 = tid & 63;
#pragma unroll
  for (int j = 0; j < 4; ++j) {
    int col = j * 64 + c4;
    float4 a = make_float4(0.f, 0.f, 0.f, 0.f);
    const float* pb = part + ((size_t)((b0 + bb) * cNC) * cH + h) * cE + (size_t)col * 4;
#pragma unroll
    for (int ck = 0; ck < cNC; ++ck) {
      float4 v = *(const float4*)(pb + (size_t)ck * cH * cE);
      a.x += v.x; a.y += v.y; a.z += v.z; a.w += v.w;
    }
    ((float4*)yl[bb])[col] = a;
  }
  __syncthreads();
  int d = tid >> 2, bi = tid & 3;
  const float* wr = w + (size_t)(2 * cE + h * cD + d) * cE;
  const float4* yr = (const float4*)yl[bi];
  float a0 = 0.f, a1 = 0.f;
#pragma unroll 4
  for (int e4 = 0; e4 < 256; e4 += 2) {
    float4 wv4 = ((const float4*)wr)[e4];
    float4 yv = yr[e4];
    a0 = fmaf(wv4.x, yv.x, a0); a0 = fmaf(wv4.y, yv.y, a0);
    a0 = fmaf(wv4.z, yv.z, a0); a0 = fmaf(wv4.w, yv.w, a0);
    float4 wv5 = ((const float4*)wr)[e4 + 1];
    float4 yv5 = yr[e4 + 1];
    a1 = fmaf(wv5.x, yv5.x, a1); a1 = fmaf(wv5.y, yv5.y, a1);
    a1 = fmaf(wv5.z, yv5.z, a1); a1 = fmaf(wv5.w, yv5.w, a1);
  }
  ctx[(size_t)(b0 + bi) * cE + h * cD + d] = a0 + a1 + bvec[2 * cE + h * cD + d];
}

// ---------------- Kernel 6: out[b,:] = out_w @ ctx[b,:] + out_b ----------------
__global__ __launch_bounds__(256) void k6_out(const float* __restrict__ w,
                                              const float* __restrict__ bvec,
                                              const float* __restrict__ ctx,
                                              float* __restrict__ out) {
  int b = blockIdx.x >> 3, br = blockIdx.x & 7;
  int tid = threadIdx.x;
  __shared__ float cl[cE];
  ((float4*)cl)[tid] = ((const float4*)(ctx + (size_t)b * cE))[tid];
  __syncthreads();
  int wid = tid >> 6, lane = tid & 63;
  for (int i = 0; i < 32; ++i) {
    int row = br * 128 + wid * 32 + i;
    const float* wr = w + (size_t)row * cE + lane * 16;
    const float* cr = cl + lane * 16;
    float partial = 0.f;
#pragma unroll
    for (int j = 0; j < 4; ++j) {
      float4 wv = *(const float4*)(wr + j * 4);
      float4 cv = *(const float4*)(cr + j * 4);
      partial = fmaf(wv.x, cv.x, partial); partial = fmaf(wv.y, cv.y, partial);
      partial = fmaf(wv.z, cv.z, partial); partial = fmaf(wv.w, cv.w, partial);
    }
    partial = wave_sum64(partial);
    if (lane == 0) out[(size_t)b * cE + row] = partial + bvec[row];
  }
}

extern "C" void kernel_launch(void* const* d_in, const int* in_sizes, int n_in,
                              void* d_out, int out_size, void* d_ws, size_t ws_size,
                              hipStream_t stream) {
  const float* x = (const float*)d_in[0];
  const int* mask = (const int*)d_in[1];
  const float* in_proj_w = (const float*)d_in[2];
  const float* in_proj_b = (const float*)d_in[3];
  const float* out_w = (const float*)d_in[4];
  const float* out_b = (const float*)d_in[5];
  float* out = (float*)d_out;
  float* W = (float*)d_ws;

  float* p = W + OFF_P;
  float* cb = W + OFF_C;
  float* q = W + OFF_Q;
  float* scores = W + OFF_SC;
  float* statsM = W + OFF_SM;
  float* statsL = W + OFF_SL;
  float* Mf = W + OFF_MF;
  float* iLf = W + OFF_IL;
  float* ctx = W + OFF_CTX;
  float* part = W + OFF_PART;

  k1a_q<<<256, 256, 0, stream>>>(x, in_proj_w, in_proj_b, q);
  k1b_p<<<256, 256, 0, stream>>>(in_proj_w, in_proj_b, q, p, cb);
  k2_scores<<<512, 256, 0, stream>>>(x, p, cb, mask, scores, statsM, statsL);
  k3t_stats<<<8, 64, 0, stream>>>(statsM, statsL, Mf, iLf);
  k4_wsum<<<512, 256, 0, stream>>>(x, scores, Mf, iLf, part, out);
  k5_ctx<<<128, 256, 0, stream>>>(in_proj_w, in_proj_b, part, ctx);
  k6_out<<<256, 256, 0, stream>>>(out_w, out_b, ctx, out);
}

// Round 6
// 345.180 us; speedup vs baseline: 1.9233x; 1.1960x over previous
//
#include <hip/hip_runtime.h>
#include <math.h>

// AttentionPooling: B=32 S=4096 E=1024 H=16 D=64
// scores[b,h,s] = (Wk_h^T q[b,h]).x[b,s]/8 ; ctx[b,h] = Wv_h (sum_s attn x[b,s]) + bv
// kfuse2: ONE kernel per (b, 256-s chunk): k2-style score phase + in-kernel chunk
// softmax stats + k4-style weighted-sum consuming the L2/L3-warm chunk. x cold-read once.

constexpr int cB = 32, cS = 4096, cE = 1024, cH = 16, cD = 64, cNC = 16;

// ws layout in floats
constexpr size_t OFF_P    = 0;                     // B*H*E   = 524288
constexpr size_t OFF_C    = OFF_P + 524288;        // B*H     = 512
constexpr size_t OFF_Q    = OFF_C + 512;           // B*E     = 32768
constexpr size_t OFF_SC   = OFF_Q + 32768;         // B*H*S   = 2097152 masked scores
constexpr size_t OFF_SM   = OFF_SC + 2097152;      // B*H*NC  = 8192 chunk max
constexpr size_t OFF_SL   = OFF_SM + 8192;         // B*H*NC  = 8192 chunk expsum
constexpr size_t OFF_MF   = OFF_SL + 8192;         // B*H     = 512 row max
constexpr size_t OFF_IL   = OFF_MF + 512;          // B*H     = 512 inv rowsum
constexpr size_t OFF_CTX  = OFF_IL + 512;          // B*E     = 32768
constexpr size_t OFF_PART = OFF_CTX + 32768;       // B*NC*H*E = 8388608

__device__ inline float wave_max64(float v) {
#pragma unroll
  for (int m = 1; m < 64; m <<= 1) v = fmaxf(v, __shfl_xor(v, m));
  return v;
}
__device__ inline float wave_sum64(float v) {
#pragma unroll
  for (int m = 1; m < 64; m <<= 1) v += __shfl_xor(v, m);
  return v;
}

// ---------------- Kernel 1a: q[b,:] = Wq @ x[b,0,:] + bq ----------------
__global__ __launch_bounds__(256) void k1a_q(const float* __restrict__ x,
                                             const float* __restrict__ w,
                                             const float* __restrict__ bias,
                                             float* __restrict__ q) {
  int b = blockIdx.x >> 3, blk = blockIdx.x & 7;
  int tid = threadIdx.x;
  __shared__ float x0[cE];
  ((float4*)x0)[tid] = ((const float4*)(x + (size_t)b * cS * cE))[tid];
  __syncthreads();
  int row = blk * 128 + (tid >> 1);
  int half = tid & 1;
  const float* wr = w + (size_t)row * cE + half * 512;
  const float* xl = x0 + half * 512;
  float acc = 0.f;
#pragma unroll 4
  for (int j = 0; j < 128; ++j) {
    float4 a = *(const float4*)(wr + j * 4);
    float4 xv = *(const float4*)(xl + j * 4);
    acc = fmaf(a.x, xv.x, acc); acc = fmaf(a.y, xv.y, acc);
    acc = fmaf(a.z, xv.z, acc); acc = fmaf(a.w, xv.w, acc);
  }
  float tot = acc + __shfl_xor(acc, 1);
  if (!half) q[b * cE + row] = tot + bias[row];
}

// ---------------- Kernel 1b: p[b,h,e] = 0.125 * sum_d Wk[h*64+d, e] q[b, h*64+d] ------
__global__ __launch_bounds__(256) void k1b_p(const float* __restrict__ w,
                                             const float* __restrict__ bvec,
                                             const float* __restrict__ q,
                                             float* __restrict__ p,
                                             float* __restrict__ cb) {
  int b = blockIdx.x >> 3, sub = blockIdx.x & 7;
  int ec = sub >> 1, hh = sub & 1;
  int tid = threadIdx.x;
  int e = ec * 256 + tid;
  __shared__ float ql[cE];
  ((float4*)ql)[tid] = ((const float4*)(q + (size_t)b * cE))[tid];
  __syncthreads();
  for (int hi = 0; hi < 8; ++hi) {
    int h = hh * 8 + hi;
    float acc = 0.f;
    const float* wb = w + (size_t)(cE + h * cD) * cE + e;
    const float* qh = ql + h * cD;
#pragma unroll 8
    for (int d = 0; d < cD; ++d) acc = fmaf(wb[(size_t)d * cE], qh[d], acc);
    p[(size_t)(b * cH + h) * cE + e] = 0.125f * acc;
  }
  if (ec == 0 && tid < 8) {
    int h = hh * 8 + tid;
    float cacc = 0.f;
    for (int d = 0; d < cD; ++d) cacc = fmaf(ql[h * cD + d], bvec[cE + h * cD + d], cacc);
    cb[b * cH + h] = 0.125f * cacc;
  }
}

// ---------------- kfuse2: scores + chunk stats + weighted sum, one x-pass ------------
// grid 512 = B*16 s-chunks of 256, block 256.
// Stage 1 (k2-proven): 64 s-threads x 4 h-waves, xT dbuf 2x32KB swizzled, scalar-p.
// Then: mask, score store, wave (m,l), ex table in LDS (overlaid on dead xT[0]).
// Stage 2 (k4-proven): thread owns 4 e x 16 h; re-reads own chunk (cache-warm);
// part[b,ck,h,e] = sum_s exp(score - m_ck) x[s,e].
__global__ __launch_bounds__(256) void kfuse2(const float* __restrict__ x,
                                              const float* __restrict__ p,
                                              const float* __restrict__ cbias,
                                              const int* __restrict__ mask,
                                              float* __restrict__ scores,
                                              float* __restrict__ statsM,
                                              float* __restrict__ statsL,
                                              float* __restrict__ part) {
  __shared__ __align__(16) float smem[16384];   // 64 KB: xT dbuf; later al overlays [0..5120)
  int bx = blockIdx.x;
  int b = bx >> 4, sc = bx & 15;
  int s_base = sc * 256;
  int tid = threadIdx.x;
  int s_t = tid & 63, h_t = tid >> 6;
  int h0 = __builtin_amdgcn_readfirstlane(h_t * 4);
  float acc[4][4];
#pragma unroll
  for (int i = 0; i < 4; ++i)
#pragma unroll
    for (int j = 0; j < 4; ++j) acc[i][j] = 0.f;

  const float* xb = x + ((size_t)b * cS + s_base) * cE;
  const float* __restrict__ pu = p + (size_t)(b * cH + h0) * cE;

  float4 sv[8];
  int r_ = tid >> 3, c4_ = tid & 7;

#pragma unroll
  for (int i = 0; i < 8; ++i)
    sv[i] = *(const float4*)(xb + (size_t)(i * 32 + r_) * cE + c4_ * 4);
  {
    float* xd = smem;
#pragma unroll
    for (int i = 0; i < 8; ++i) {
      int r = i * 32 + r_;
      float vv[4] = {sv[i].x, sv[i].y, sv[i].z, sv[i].w};
#pragma unroll
      for (int j = 0; j < 4; ++j) {
        int e = c4_ * 4 + j;
        int f = (e ^ (e >> 4)) & 15;
        xd[e * 256 + ((((r >> 2) ^ f) << 2) | (r & 3))] = vv[j];
      }
    }
  }
  __syncthreads();

  for (int kt = 1; kt <= 32; ++kt) {
    if (kt < 32) {
#pragma unroll
      for (int i = 0; i < 8; ++i)
        sv[i] = *(const float4*)(xb + (size_t)(i * 32 + r_) * cE + kt * 32 + c4_ * 4);
    }
    {
      const float* xs = smem + ((kt - 1) & 1) * 8192;
      const int kb = (kt - 1) * 32;
#pragma unroll 8
      for (int e = 0; e < 32; ++e) {
        int f = (e ^ (e >> 4)) & 15;
        float4 xv = *(const float4*)&xs[e * 256 + ((s_t ^ f) << 2)];
        float p0 = pu[kb + e];
        float p1 = pu[cE + kb + e];
        float p2 = pu[2 * cE + kb + e];
        float p3 = pu[3 * cE + kb + e];
        float xa[4] = {xv.x, xv.y, xv.z, xv.w};
        float pa[4] = {p0, p1, p2, p3};
#pragma unroll
        for (int si = 0; si < 4; ++si)
#pragma unroll
          for (int hj = 0; hj < 4; ++hj) acc[si][hj] = fmaf(xa[si], pa[hj], acc[si][hj]);
      }
    }
    if (kt < 32) {
      float* xd = smem + (kt & 1) * 8192;
#pragma unroll
      for (int i = 0; i < 8; ++i) {
        int r = i * 32 + r_;
        float vv[4] = {sv[i].x, sv[i].y, sv[i].z, sv[i].w};
#pragma unroll
        for (int j = 0; j < 4; ++j) {
          int e = c4_ * 4 + j;
          int f = (e ^ (e >> 4)) & 15;
          xd[e * 256 + ((((r >> 2) ^ f) << 2) | (r & 3))] = vv[j];
        }
      }
    }
    __syncthreads();
  }

  // ---- epilogue A: bias, mask, store scores, chunk (m,l), ex table into al ----
  // al overlays smem[0..5120) = xT[0], dead after the last barrier above.
  float* al = smem;   // [256][20]
  float4 cv = *(const float4*)(cbias + b * cH + h0);
  float ca[4] = {cv.x, cv.y, cv.z, cv.w};
  int4 m4 = *(const int4*)(mask + (size_t)b * cS + s_base + s_t * 4);
#pragma unroll
  for (int hj = 0; hj < 4; ++hj) {
    float v0 = m4.x ? -1e30f : acc[0][hj] + ca[hj];
    float v1 = m4.y ? -1e30f : acc[1][hj] + ca[hj];
    float v2 = m4.z ? -1e30f : acc[2][hj] + ca[hj];
    float v3 = m4.w ? -1e30f : acc[3][hj] + ca[hj];
    *(float4*)(scores + (size_t)(b * cH + h0 + hj) * cS + s_base + s_t * 4) =
        make_float4(v0, v1, v2, v3);
    float mx = fmaxf(fmaxf(v0, v1), fmaxf(v2, v3));
    float wm = wave_max64(mx);
    float e0 = __expf(v0 - wm), e1 = __expf(v1 - wm);
    float e2 = __expf(v2 - wm), e3 = __expf(v3 - wm);
    float wsum = wave_sum64(e0 + e1 + e2 + e3);
    if (s_t == 0) {
      statsM[(size_t)(b * cH + h0 + hj) * cNC + sc] = wm;
      statsL[(size_t)(b * cH + h0 + hj) * cNC + sc] = wsum;
    }
    int sl = s_t * 4;
    al[(sl + 0) * 20 + h0 + hj] = e0;
    al[(sl + 1) * 20 + h0 + hj] = e1;
    al[(sl + 2) * 20 + h0 + hj] = e2;
    al[(sl + 3) * 20 + h0 + hj] = e3;
  }
  __syncthreads();   // al ready

  // ---- stage 2: weighted sum over the (cache-warm) chunk ----
  float4 acc2[16];
#pragma unroll
  for (int h = 0; h < cH; ++h) acc2[h] = make_float4(0.f, 0.f, 0.f, 0.f);
  const float* xg = xb + (size_t)tid * 4;
#pragma unroll 4
  for (int s = 0; s < 256; ++s) {
    float4 xv = *(const float4*)(xg + (size_t)s * cE);
    const float4* ar = (const float4*)(al + s * 20);
    float4 a0 = ar[0], a1 = ar[1], a2 = ar[2], a3 = ar[3];
    float aa[16] = {a0.x, a0.y, a0.z, a0.w, a1.x, a1.y, a1.z, a1.w,
                    a2.x, a2.y, a2.z, a2.w, a3.x, a3.y, a3.z, a3.w};
#pragma unroll
    for (int h = 0; h < cH; ++h) {
      acc2[h].x = fmaf(aa[h], xv.x, acc2[h].x);
      acc2[h].y = fmaf(aa[h], xv.y, acc2[h].y);
      acc2[h].z = fmaf(aa[h], xv.z, acc2[h].z);
      acc2[h].w = fmaf(aa[h], xv.w, acc2[h].w);
    }
  }
  float* pb = part + ((size_t)(b * cNC + sc) * cH) * cE + (size_t)tid * 4;
#pragma unroll
  for (int h = 0; h < cH; ++h) *(float4*)(pb + (size_t)h * cE) = acc2[h];
}

// ---------------- k5: combine chunks -> y; ctx = Wv_h y + bv; emit Mf/iLf ----------
// grid 512 = (b,h). R4-proven structure (coalesced w rows, wave_sum64 GEMV).
__global__ __launch_bounds__(256) void k5_ctx(const float* __restrict__ w,
                                              const float* __restrict__ bvec,
                                              const float* __restrict__ part,
                                              const float* __restrict__ statsM,
                                              const float* __restrict__ statsL,
                                              float* __restrict__ ctx,
                                              float* __restrict__ Mf,
                                              float* __restrict__ iLf) {
  int b = blockIdx.x >> 4, h = blockIdx.x & 15;
  int bh = b * cH + h;
  int tid = threadIdx.x;
  __shared__ float yl[cE];
  float M = -3e38f;
#pragma unroll
  for (int c = 0; c < cNC; ++c) M = fmaxf(M, statsM[bh * cNC + c]);
  float L = 0.f;
  float wgt[cNC];
#pragma unroll
  for (int c = 0; c < cNC; ++c) {
    wgt[c] = __expf(statsM[bh * cNC + c] - M);
    L += statsL[bh * cNC + c] * wgt[c];
  }
  float iL = 1.0f / L;
  if (tid == 0) { Mf[bh] = M; iLf[bh] = iL; }
  float4 a = make_float4(0.f, 0.f, 0.f, 0.f);
  const float* pb = part + (size_t)b * cNC * cH * cE + (size_t)h * cE + (size_t)tid * 4;
#pragma unroll
  for (int c = 0; c < cNC; ++c) {
    float4 v = *(const float4*)(pb + (size_t)c * cH * cE);
    a.x = fmaf(v.x, wgt[c], a.x); a.y = fmaf(v.y, wgt[c], a.y);
    a.z = fmaf(v.z, wgt[c], a.z); a.w = fmaf(v.w, wgt[c], a.w);
  }
  a.x *= iL; a.y *= iL; a.z *= iL; a.w *= iL;
  *(float4*)(yl + tid * 4) = a;
  __syncthreads();
  int wid = tid >> 6, lane = tid & 63;
  for (int i = 0; i < 16; ++i) {
    int d = wid * 16 + i;
    const float* wr = w + (size_t)(2 * cE + h * cD + d) * cE + lane * 16;
    const float* yr = yl + lane * 16;
    float partial = 0.f;
#pragma unroll
    for (int j = 0; j < 4; ++j) {
      float4 wv = *(const float4*)(wr + j * 4);
      float4 yv = *(const float4*)(yr + j * 4);
      partial = fmaf(wv.x, yv.x, partial); partial = fmaf(wv.y, yv.y, partial);
      partial = fmaf(wv.z, yv.z, partial); partial = fmaf(wv.w, yv.w, partial);
    }
    partial = wave_sum64(partial);
    if (lane == 0) ctx[b * cE + h * cD + d] = partial + bvec[2 * cE + h * cD + d];
  }
}

// ---------------- kmean: attn_weights[b,0,s] = mean_h exp(score - M_h)*iL_h ----------
__global__ __launch_bounds__(256) void kmean(const float* __restrict__ scores,
                                             const float* __restrict__ Mf,
                                             const float* __restrict__ iLf,
                                             float* __restrict__ out) {
  int idx = blockIdx.x * 256 + threadIdx.x;
  int b = idx >> 12, s = idx & 4095;
  float sum = 0.f;
#pragma unroll
  for (int h = 0; h < cH; ++h) {
    float v = scores[(size_t)(b * cH + h) * cS + s];
    sum += __expf(v - Mf[b * cH + h]) * iLf[b * cH + h];
  }
  out[cB * cE + (size_t)b * cS + s] = sum * (1.0f / 16.0f);
}

// ---------------- k6: out[b,:] = out_w @ ctx[b,:] + out_b ----------------
__global__ __launch_bounds__(256) void k6_out(const float* __restrict__ w,
                                              const float* __restrict__ bvec,
                                              const float* __restrict__ ctx,
                                              float* __restrict__ out) {
  int b = blockIdx.x >> 3, br = blockIdx.x & 7;
  int tid = threadIdx.x;
  __shared__ float cl[cE];
  ((float4*)cl)[tid] = ((const float4*)(ctx + (size_t)b * cE))[tid];
  __syncthreads();
  int wid = tid >> 6, lane = tid & 63;
  for (int i = 0; i < 32; ++i) {
    int row = br * 128 + wid * 32 + i;
    const float* wr = w + (size_t)row * cE + lane * 16;
    const float* cr = cl + lane * 16;
    float partial = 0.f;
#pragma unroll
    for (int j = 0; j < 4; ++j) {
      float4 wv = *(const float4*)(wr + j * 4);
      float4 cv = *(const float4*)(cr + j * 4);
      partial = fmaf(wv.x, cv.x, partial); partial = fmaf(wv.y, cv.y, partial);
      partial = fmaf(wv.z, cv.z, partial); partial = fmaf(wv.w, cv.w, partial);
    }
    partial = wave_sum64(partial);
    if (lane == 0) out[(size_t)b * cE + row] = partial + bvec[row];
  }
}

extern "C" void kernel_launch(void* const* d_in, const int* in_sizes, int n_in,
                              void* d_out, int out_size, void* d_ws, size_t ws_size,
                              hipStream_t stream) {
  const float* x = (const float*)d_in[0];
  const int* mask = (const int*)d_in[1];
  const float* in_proj_w = (const float*)d_in[2];
  const float* in_proj_b = (const float*)d_in[3];
  const float* out_w = (const float*)d_in[4];
  const float* out_b = (const float*)d_in[5];
  float* out = (float*)d_out;
  float* W = (float*)d_ws;

  float* p = W + OFF_P;
  float* cb = W + OFF_C;
  float* q = W + OFF_Q;
  float* scores = W + OFF_SC;
  float* statsM = W + OFF_SM;
  float* statsL = W + OFF_SL;
  float* Mf = W + OFF_MF;
  float* iLf = W + OFF_IL;
  float* ctx = W + OFF_CTX;
  float* part = W + OFF_PART;

  k1a_q<<<256, 256, 0, stream>>>(x, in_proj_w, in_proj_b, q);
  k1b_p<<<256, 256, 0, stream>>>(in_proj_w, in_proj_b, q, p, cb);
  kfuse2<<<512, 256, 0, stream>>>(x, p, cb, mask, scores, statsM, statsL, part);
  k5_ctx<<<512, 256, 0, stream>>>(in_proj_w, in_proj_b, part, statsM, statsL, ctx, Mf, iLf);
  kmean<<<512, 256, 0, stream>>>(scores, Mf, iLf, out);
  k6_out<<<256, 256, 0, stream>>>(out_w, out_b, ctx, out);
}

// Round 8
// 301.290 us; speedup vs baseline: 2.2035x; 1.1457x over previous
//
#include <hip/hip_runtime.h>
#include <math.h>

// AttentionPooling: B=32 S=4096 E=1024 H=16 D=64
// scores[b,h,s] = (Wk_h^T q[b,h]).x[b,s]/8 ; ctx[b,h] = Wv_h (sum_s attn x[b,s]) + bv
// kfuse2: per (b, 256-s chunk): retiled score stage (2s x 8h waves, 2x LDS amp) +
// chunk softmax stats + warm weighted-sum re-read. Weight GEMVs batched over b
// (weights read once): kgemm32 (q / ctx / out), kp_gemm (p + cb).
// R8: fix kgemm32 a_lds stride (1028, was 260 -> overlap/overflow) and kp_gemm
// w_lds stride (260, was 258 -> misaligned b128 LDS reads).

constexpr int cB = 32, cS = 4096, cE = 1024, cH = 16, cD = 64, cNC = 16;

// ws layout in floats
constexpr size_t OFF_P    = 0;                     // B*H*E   = 524288
constexpr size_t OFF_C    = OFF_P + 524288;        // B*H     = 512
constexpr size_t OFF_Q    = OFF_C + 512;           // B*E     = 32768
constexpr size_t OFF_SC   = OFF_Q + 32768;         // B*H*S   = 2097152 masked scores
constexpr size_t OFF_SM   = OFF_SC + 2097152;      // B*H*NC  = 8192 chunk max
constexpr size_t OFF_SL   = OFF_SM + 8192;         // B*H*NC  = 8192 chunk expsum
constexpr size_t OFF_MF   = OFF_SL + 8192;         // B*H     = 512 row max
constexpr size_t OFF_IL   = OFF_MF + 512;          // B*H     = 512 inv rowsum
constexpr size_t OFF_CTX  = OFF_IL + 512;          // B*E     = 32768
constexpr size_t OFF_PART = OFF_CTX + 32768;       // B*NC*H*E = 8388608
constexpr size_t OFF_Y    = OFF_PART + 8388608;    // B*H*E   = 524288

__device__ inline float wave_max64(float v) {
#pragma unroll
  for (int m = 1; m < 64; m <<= 1) v = fmaxf(v, __shfl_xor(v, m));
  return v;
}
__device__ inline float wave_sum64(float v) {
#pragma unroll
  for (int m = 1; m < 64; m <<= 1) v += __shfl_xor(v, m);
  return v;
}

// ---------------- kgemm32: C[32, n-tile16] = A[32,1024] @ W^T rows + bias ------------
// grid 64 n-tiles of 16 W-rows. A staged whole in LDS ([32][1028], 131.6 KB); wave w
// owns K-range [w*256,+256); lane = (ng 0..3, bp 0..15) owns 4 n x 2 b; bp-rotation of
// the e4 index de-conflicts LDS A-reads; W global reads coalesced. 4-way K-reduce LDS.
__global__ __launch_bounds__(256) void kgemm32(const float* __restrict__ A,
                                               size_t aRowStride, int aBlk,
                                               const float* __restrict__ Wm, int wRow0,
                                               const float* __restrict__ bias,
                                               float* __restrict__ C) {
  __shared__ float a_lds[32 * 1028];
  __shared__ float red[4][16][32];
  int tid = threadIdx.x;
  int bx = blockIdx.x;
  const float* abase = A + (aBlk ? ((size_t)(bx >> 2) * 1024) : (size_t)0);

  // stage A: row j (=b), col tid*4
#pragma unroll 4
  for (int j = 0; j < 32; ++j) {
    float4 v = *(const float4*)(abase + (size_t)j * aRowStride + (size_t)tid * 4);
    *(float4*)(a_lds + j * 1028 + tid * 4) = v;
  }
  __syncthreads();

  int wv = tid >> 6, lane = tid & 63;
  int ng = lane >> 4, bp = lane & 15;
  float acc[4][2];
#pragma unroll
  for (int j = 0; j < 4; ++j) { acc[j][0] = 0.f; acc[j][1] = 0.f; }

  const float* w0 = Wm + (size_t)(wRow0 + bx * 16 + ng * 4) * 1024;
#pragma unroll 4
  for (int i = 0; i < 64; ++i) {
    int e4 = wv * 64 + ((i + bp) & 63);
    float4 a0 = *(const float4*)(a_lds + (bp * 2 + 0) * 1028 + e4 * 4);
    float4 a1 = *(const float4*)(a_lds + (bp * 2 + 1) * 1028 + e4 * 4);
#pragma unroll
    for (int j = 0; j < 4; ++j) {
      float4 w4 = *(const float4*)(w0 + (size_t)j * 1024 + e4 * 4);
      acc[j][0] = fmaf(w4.x, a0.x, acc[j][0]); acc[j][0] = fmaf(w4.y, a0.y, acc[j][0]);
      acc[j][0] = fmaf(w4.z, a0.z, acc[j][0]); acc[j][0] = fmaf(w4.w, a0.w, acc[j][0]);
      acc[j][1] = fmaf(w4.x, a1.x, acc[j][1]); acc[j][1] = fmaf(w4.y, a1.y, acc[j][1]);
      acc[j][1] = fmaf(w4.z, a1.z, acc[j][1]); acc[j][1] = fmaf(w4.w, a1.w, acc[j][1]);
    }
  }
#pragma unroll
  for (int j = 0; j < 4; ++j) {
    red[wv][ng * 4 + j][bp * 2 + 0] = acc[j][0];
    red[wv][ng * 4 + j][bp * 2 + 1] = acc[j][1];
  }
  __syncthreads();
#pragma unroll
  for (int t = 0; t < 2; ++t) {
    int idx = t * 256 + tid;
    int n = idx >> 5, b = idx & 31;
    float s = red[0][n][b] + red[1][n][b] + red[2][n][b] + red[3][n][b] +
              bias[bx * 16 + n];
    C[(size_t)b * 1024 + bx * 16 + n] = s;
  }
}

// ---------------- kp_gemm: p[b,h,et*256+e] = 0.125 * sum_d Wk[h*64+d,e] q[b,h*64+d] ---
// grid 64 = (h 16) x (e-tile 4 of 256). Wk tile + q slice staged; thread (b, eg) owns
// 1 b x 32 e. cb folded in (et==0 blocks). Wk read once across the grid.
__global__ __launch_bounds__(256) void kp_gemm(const float* __restrict__ w,
                                               const float* __restrict__ bvec,
                                               const float* __restrict__ q,
                                               float* __restrict__ p,
                                               float* __restrict__ cb) {
  __shared__ float w_lds[64 * 260];
  __shared__ float q_lds[32 * 65];
  int h = blockIdx.x >> 2, et = blockIdx.x & 3;
  int tid = threadIdx.x;
  // stage Wk tile [64 d][256 e]
#pragma unroll 4
  for (int j = 0; j < 16; ++j) {
    int idx = j * 256 + tid;
    int row = idx >> 6, c4 = idx & 63;
    float4 v = *(const float4*)(w + (size_t)(1024 + h * 64 + row) * 1024 + et * 256 + c4 * 4);
    *(float4*)(w_lds + row * 260 + c4 * 4) = v;
  }
  // stage q slice [32 b][64 d]
#pragma unroll
  for (int jj = 0; jj < 2; ++jj) {
    int idx = jj * 256 + tid;
    int row = idx >> 4, c4 = idx & 15;
    float4 v = *(const float4*)(q + (size_t)row * 1024 + h * 64 + c4 * 4);
    *(float4*)(q_lds + row * 65 + c4 * 4) = v;
  }
  __syncthreads();

  int b = tid & 31, eg = tid >> 5;   // eg 0..7, 32 e each
  float4 acc[8];
#pragma unroll
  for (int j = 0; j < 8; ++j) acc[j] = make_float4(0.f, 0.f, 0.f, 0.f);
#pragma unroll 4
  for (int d = 0; d < 64; ++d) {
    float qv = q_lds[b * 65 + d];
#pragma unroll
    for (int j = 0; j < 8; ++j) {
      float4 wv4 = *(const float4*)(w_lds + d * 260 + eg * 32 + j * 4);
      acc[j].x = fmaf(wv4.x, qv, acc[j].x);
      acc[j].y = fmaf(wv4.y, qv, acc[j].y);
      acc[j].z = fmaf(wv4.z, qv, acc[j].z);
      acc[j].w = fmaf(wv4.w, qv, acc[j].w);
    }
  }
  float* pb = p + (size_t)(b * cH + h) * cE + et * 256 + eg * 32;
#pragma unroll
  for (int j = 0; j < 8; ++j) {
    float4 o = make_float4(acc[j].x * 0.125f, acc[j].y * 0.125f,
                           acc[j].z * 0.125f, acc[j].w * 0.125f);
    *(float4*)(pb + j * 4) = o;
  }
  if (et == 0 && tid < 32) {
    int bb = tid;
    float cacc = 0.f;
    for (int d = 0; d < 64; ++d)
      cacc = fmaf(q_lds[bb * 65 + d], bvec[1024 + h * 64 + d], cacc);
    cb[bb * cH + h] = 0.125f * cacc;
  }
}

// ---------------- kfuse2: scores + chunk stats + weighted sum, one cold x-pass --------
// grid 512 = B*16 s-chunks of 256, block 256 = 4 waves.
// Stage 1 retiled: wave = (hg = wv>>1 -> h0 = hg*8, sg = wv&1 -> s-half); lane owns
// 2 consecutive s x 8 h; b64 LDS reads (2x amp). p scalar via uniform h0.
// Epilogue: combined-max handshake (2 barriers), ex table al[256][20].
// Stage 2: thread owns 4 e x 16 h, re-reads own chunk hottest-first.
__global__ __launch_bounds__(256) void kfuse2(const float* __restrict__ x,
                                              const float* __restrict__ p,
                                              const float* __restrict__ cbias,
                                              const int* __restrict__ mask,
                                              float* __restrict__ scores,
                                              float* __restrict__ statsM,
                                              float* __restrict__ statsL,
                                              float* __restrict__ part) {
  __shared__ __align__(16) float smem[16384];   // 64 KB xT dbuf; al overlays [0..5120)
  __shared__ float sml_m[4][8], sml_l[4][8];
  int bx = blockIdx.x;
  int b = bx >> 4, sc = bx & 15;
  int s_base = sc * 256;
  int tid = threadIdx.x;
  int wv = tid >> 6, lane = tid & 63;
  int sg = wv & 1, hg = wv >> 1;
  int h0 = __builtin_amdgcn_readfirstlane(hg * 8);
  float acc[2][8];
#pragma unroll
  for (int i = 0; i < 2; ++i)
#pragma unroll
    for (int j = 0; j < 8; ++j) acc[i][j] = 0.f;

  const float* xb = x + ((size_t)b * cS + s_base) * cE;
  const float* __restrict__ pu = p + (size_t)(b * cH + h0) * cE;

  float4 sv[8];
  int r_ = tid >> 3, c4_ = tid & 7;

  // prologue: stage kt=0 (transposed + f4-group swizzle, unchanged from proven k2)
#pragma unroll
  for (int i = 0; i < 8; ++i)
    sv[i] = *(const float4*)(xb + (size_t)(i * 32 + r_) * cE + c4_ * 4);
  {
    float* xd = smem;
#pragma unroll
    for (int i = 0; i < 8; ++i) {
      int r = i * 32 + r_;
      float vv[4] = {sv[i].x, sv[i].y, sv[i].z, sv[i].w};
#pragma unroll
      for (int j = 0; j < 4; ++j) {
        int e = c4_ * 4 + j;
        int f = (e ^ (e >> 4)) & 15;
        xd[e * 256 + ((((r >> 2) ^ f) << 2) | (r & 3))] = vv[j];
      }
    }
  }
  __syncthreads();

  int gbase = sg * 32 + (lane >> 1);    // f4-group of this lane's s-pair
  int goff = (lane & 1) << 1;           // offset within group
  for (int kt = 1; kt <= 32; ++kt) {
    if (kt < 32) {
#pragma unroll
      for (int i = 0; i < 8; ++i)
        sv[i] = *(const float4*)(xb + (size_t)(i * 32 + r_) * cE + kt * 32 + c4_ * 4);
    }
    {
      const float* xs = smem + ((kt - 1) & 1) * 8192;
      const int kb = (kt - 1) * 32;
#pragma unroll 8
      for (int e = 0; e < 32; ++e) {
        int f = (e ^ (e >> 4)) & 15;
        float2 xv = *(const float2*)&xs[e * 256 + (((gbase ^ f) << 2) | goff)];
        float p0 = pu[kb + e];
        float p1 = pu[cE + kb + e];
        float p2 = pu[2 * cE + kb + e];
        float p3 = pu[3 * cE + kb + e];
        float p4 = pu[4 * cE + kb + e];
        float p5 = pu[5 * cE + kb + e];
        float p6 = pu[6 * cE + kb + e];
        float p7 = pu[7 * cE + kb + e];
        float pa[8] = {p0, p1, p2, p3, p4, p5, p6, p7};
#pragma unroll
        for (int hj = 0; hj < 8; ++hj) {
          acc[0][hj] = fmaf(xv.x, pa[hj], acc[0][hj]);
          acc[1][hj] = fmaf(xv.y, pa[hj], acc[1][hj]);
        }
      }
    }
    if (kt < 32) {
      float* xd = smem + (kt & 1) * 8192;
#pragma unroll
      for (int i = 0; i < 8; ++i) {
        int r = i * 32 + r_;
        float vv[4] = {sv[i].x, sv[i].y, sv[i].z, sv[i].w};
#pragma unroll
        for (int j = 0; j < 4; ++j) {
          int e = c4_ * 4 + j;
          int f = (e ^ (e >> 4)) & 15;
          xd[e * 256 + ((((r >> 2) ^ f) << 2) | (r & 3))] = vv[j];
        }
      }
    }
    __syncthreads();
  }

  // ---- epilogue: bias, mask, scores, combined-max stats, ex table ----
  float* al = smem;   // [256][20], overlays dead xT
  int sl_loc = sg * 128 + lane * 2;          // chunk-local s of pair
  int sl = s_base + sl_loc;                  // global s
  float ca[8];
  {
    float4 c0 = *(const float4*)(cbias + b * cH + h0);
    float4 c1 = *(const float4*)(cbias + b * cH + h0 + 4);
    ca[0] = c0.x; ca[1] = c0.y; ca[2] = c0.z; ca[3] = c0.w;
    ca[4] = c1.x; ca[5] = c1.y; ca[6] = c1.z; ca[7] = c1.w;
  }
  int2 mv = *(const int2*)(mask + (size_t)b * cS + sl);
  float vs0[8], vs1[8];
#pragma unroll
  for (int hj = 0; hj < 8; ++hj) {
    float v0 = mv.x ? -1e30f : acc[0][hj] + ca[hj];
    float v1 = mv.y ? -1e30f : acc[1][hj] + ca[hj];
    vs0[hj] = v0; vs1[hj] = v1;
    float2 o = make_float2(v0, v1);
    *(float2*)(scores + (size_t)(b * cH + h0 + hj) * cS + sl) = o;
    float wm = wave_max64(fmaxf(v0, v1));
    if (lane == 0) sml_m[wv][hj] = wm;
  }
  __syncthreads();
#pragma unroll
  for (int hj = 0; hj < 8; ++hj) {
    float mh = fmaxf(sml_m[hg * 2][hj], sml_m[hg * 2 + 1][hj]);
    float e0 = __expf(vs0[hj] - mh);
    float e1 = __expf(vs1[hj] - mh);
    float ws = wave_sum64(e0 + e1);
    if (lane == 0) sml_l[wv][hj] = ws;
    al[(sl_loc + 0) * 20 + h0 + hj] = e0;
    al[(sl_loc + 1) * 20 + h0 + hj] = e1;
  }
  __syncthreads();
  if (tid < 16) {
    int h = tid, hg2 = h >> 3, hj = h & 7;
    float mh = fmaxf(sml_m[hg2 * 2][hj], sml_m[hg2 * 2 + 1][hj]);
    float L = sml_l[hg2 * 2][hj] + sml_l[hg2 * 2 + 1][hj];
    statsM[(size_t)(b * cH + h) * cNC + sc] = mh;
    statsL[(size_t)(b * cH + h) * cNC + sc] = L;
  }

  // ---- stage 2: weighted sum, hottest-first ----
  float4 acc2[16];
#pragma unroll
  for (int h = 0; h < cH; ++h) acc2[h] = make_float4(0.f, 0.f, 0.f, 0.f);
  const float* xg = xb + (size_t)tid * 4;
#pragma unroll 4
  for (int s = 255; s >= 0; --s) {
    float4 xv = *(const float4*)(xg + (size_t)s * cE);
    const float4* ar = (const float4*)(al + s * 20);
    float4 a0 = ar[0], a1 = ar[1], a2 = ar[2], a3 = ar[3];
    float aa[16] = {a0.x, a0.y, a0.z, a0.w, a1.x, a1.y, a1.z, a1.w,
                    a2.x, a2.y, a2.z, a2.w, a3.x, a3.y, a3.z, a3.w};
#pragma unroll
    for (int h = 0; h < cH; ++h) {
      acc2[h].x = fmaf(aa[h], xv.x, acc2[h].x);
      acc2[h].y = fmaf(aa[h], xv.y, acc2[h].y);
      acc2[h].z = fmaf(aa[h], xv.z, acc2[h].z);
      acc2[h].w = fmaf(aa[h], xv.w, acc2[h].w);
    }
  }
  float* pb = part + ((size_t)(b * cNC + sc) * cH) * cE + (size_t)tid * 4;
#pragma unroll
  for (int h = 0; h < cH; ++h) *(float4*)(pb + (size_t)h * cE) = acc2[h];
}

// ---------------- k5a: y[b,h,:] = (sum_ck wgt part) * iL; emit Mf/iLf ----------------
__global__ __launch_bounds__(256) void k5a_comb(const float* __restrict__ part,
                                                const float* __restrict__ statsM,
                                                const float* __restrict__ statsL,
                                                float* __restrict__ y,
                                                float* __restrict__ Mf,
                                                float* __restrict__ iLf) {
  int b = blockIdx.x >> 4, h = blockIdx.x & 15;
  int bh = b * cH + h;
  int tid = threadIdx.x;
  float M = -3e38f;
#pragma unroll
  for (int c = 0; c < cNC; ++c) M = fmaxf(M, statsM[bh * cNC + c]);
  float L = 0.f;
  float wgt[cNC];
#pragma unroll
  for (int c = 0; c < cNC; ++c) {
    wgt[c] = __expf(statsM[bh * cNC + c] - M);
    L += statsL[bh * cNC + c] * wgt[c];
  }
  float iL = 1.0f / L;
  if (tid == 0) { Mf[bh] = M; iLf[bh] = iL; }
  float4 a = make_float4(0.f, 0.f, 0.f, 0.f);
  const float* pb = part + (size_t)b * cNC * cH * cE + (size_t)h * cE + (size_t)tid * 4;
#pragma unroll
  for (int c = 0; c < cNC; ++c) {
    float4 v = *(const float4*)(pb + (size_t)c * cH * cE);
    a.x = fmaf(v.x, wgt[c], a.x); a.y = fmaf(v.y, wgt[c], a.y);
    a.z = fmaf(v.z, wgt[c], a.z); a.w = fmaf(v.w, wgt[c], a.w);
  }
  a.x *= iL; a.y *= iL; a.z *= iL; a.w *= iL;
  *(float4*)(y + (size_t)bh * cE + (size_t)tid * 4) = a;
}

// ---------------- kmean: attn_weights[b,0,s] = mean_h exp(score - M_h)*iL_h ----------
__global__ __launch_bounds__(256) void kmean(const float* __restrict__ scores,
                                             const float* __restrict__ Mf,
                                             const float* __restrict__ iLf,
                                             float* __restrict__ out) {
  int idx = blockIdx.x * 256 + threadIdx.x;
  int b = idx >> 12, s = idx & 4095;
  float sum = 0.f;
#pragma unroll
  for (int h = 0; h < cH; ++h) {
    float v = scores[(size_t)(b * cH + h) * cS + s];
    sum += __expf(v - Mf[b * cH + h]) * iLf[b * cH + h];
  }
  out[cB * cE + (size_t)b * cS + s] = sum * (1.0f / 16.0f);
}

extern "C" void kernel_launch(void* const* d_in, const int* in_sizes, int n_in,
                              void* d_out, int out_size, void* d_ws, size_t ws_size,
                              hipStream_t stream) {
  const float* x = (const float*)d_in[0];
  const int* mask = (const int*)d_in[1];
  const float* in_proj_w = (const float*)d_in[2];
  const float* in_proj_b = (const float*)d_in[3];
  const float* out_w = (const float*)d_in[4];
  const float* out_b = (const float*)d_in[5];
  float* out = (float*)d_out;
  float* W = (float*)d_ws;

  float* p = W + OFF_P;
  float* cb = W + OFF_C;
  float* q = W + OFF_Q;
  float* scores = W + OFF_SC;
  float* statsM = W + OFF_SM;
  float* statsL = W + OFF_SL;
  float* Mf = W + OFF_MF;
  float* iLf = W + OFF_IL;
  float* ctx = W + OFF_CTX;
  float* part = W + OFF_PART;
  float* y = W + OFF_Y;

  // q[32,1024] = x[:,0,:] @ Wq^T + bq   (Wq rows 0..1023)
  kgemm32<<<64, 256, 0, stream>>>(x, (size_t)cS * cE, 0, in_proj_w, 0, in_proj_b, q);
  // p + cb  (Wk rows 1024..2047)
  kp_gemm<<<64, 256, 0, stream>>>(in_proj_w, in_proj_b, q, p, cb);
  // fused scores + stats + weighted partial sums
  kfuse2<<<512, 256, 0, stream>>>(x, p, cb, mask, scores, statsM, statsL, part);
  // combine chunks -> y, emit Mf/iLf
  k5a_comb<<<512, 256, 0, stream>>>(part, statsM, statsL, y, Mf, iLf);
  // ctx[32,1024] = y_h @ Wv_h^T + bv    (Wv rows 2048..3071; per-block A = y[:,h,:])
  kgemm32<<<64, 256, 0, stream>>>(y, (size_t)cH * cE, 1, in_proj_w, 2048,
                                  in_proj_b + 2048, ctx);
  // attn-weights mean
  kmean<<<512, 256, 0, stream>>>(scores, Mf, iLf, out);
  // out[32,1024] = ctx @ out_w^T + out_b
  kgemm32<<<64, 256, 0, stream>>>(ctx, (size_t)cE, 0, out_w, 0, out_b, out);
}